// Round 17
// baseline (1494.364 us; speedup 1.0000x reference)
//
#include <hip/hip_runtime.h>
#include <math.h>

#define B_ 8
#define T_ 16000
#define NBT 250          // time-blocks of 64 cols
#define HROWS 16512      // 512 guard rows + 16000
#define NLAY 20

typedef __attribute__((ext_vector_type(8))) short bf16x8;
typedef __attribute__((ext_vector_type(4))) float f32x4;
typedef __attribute__((ext_vector_type(4))) short sh4;

__device__ __forceinline__ unsigned short f2bf(float f){
  unsigned u = __float_as_uint(f);
  u += 0x7fffu + ((u >> 16) & 1u);          // RNE to bf16
  return (unsigned short)(u >> 16);
}
__device__ __forceinline__ float bf2f(unsigned short s){
  return __uint_as_float(((unsigned)s) << 16);
}
__device__ __forceinline__ void split2(float v, unsigned short& hi, unsigned short& lo){
  hi = f2bf(v);
  lo = f2bf(v - bf2f(hi));
}

#define MFMA(a,b,c) __builtin_amdgcn_mfma_f32_16x16x32_bf16((a),(b),(c),0,0,0)

// async global->LDS 16B per lane (dest = uniform base + lane*16, src per-lane)
__device__ __forceinline__ void gload16(const short* gsrc, short* ldst){
  __builtin_amdgcn_global_load_lds(
      (const __attribute__((address_space(1))) unsigned int*)gsrc,
      (__attribute__((address_space(3))) unsigned int*)ldst, 16, 0, 0);
}

// ---------------- prep kernels ----------------
__global__ void k_split(const float* __restrict__ src, short* __restrict__ hi,
                        short* __restrict__ lo, int n){
  int idx = blockIdx.x * 256 + threadIdx.x;
  if (idx < n){
    unsigned short h, l; split2(src[idx], h, l);
    hi[idx] = (short)h; lo[idx] = (short)l;
  }
}
// gate weights: Wg[l][row][k] : k<64 -> wdp[l][row][k], else wdc[l][row][k-64]
__global__ void k_split_gate(const float* __restrict__ wdp, const float* __restrict__ wdc,
                             short* __restrict__ hi, short* __restrict__ lo){
  int idx = blockIdx.x * 256 + threadIdx.x;
  if (idx < NLAY*128*128){
    int l   = idx >> 14;
    int rem = idx & 16383;
    int row = rem >> 7;
    int k   = rem & 127;
    float v = (k < 64) ? wdp[(l*128 + row)*64 + k] : wdc[(l*128 + row)*64 + (k-64)];
    unsigned short h, lo16; split2(v, h, lo16);
    hi[idx] = (short)h; lo[idx] = (short)lo16;
  }
}
// skip weights packed fragment-major: WSF[l][w][half][kb2][lane j][8]
__global__ void k_pack_wsf(const float* __restrict__ wsk, short* __restrict__ wsf){
  int idx = blockIdx.x * 256 + threadIdx.x;
  if (idx < NLAY*8*2*2*64*8){
    int e    = idx & 7;
    int j    = (idx >> 3) & 63;
    int kb2  = (idx >> 9) & 1;
    int half = (idx >> 10) & 1;
    int w    = (idx >> 11) & 7;
    int l    = idx >> 14;
    int row  = w*32 + half*16 + (j & 15);
    int ch   = (kb2*4 + (j >> 4))*8 + e;
    wsf[idx] = (short)f2bf(wsk[((size_t)l*256 + row)*64 + ch]);
  }
}
__global__ void k_bsum(const float* __restrict__ bsk, float* __restrict__ bsum){
  int s = threadIdx.x;
  if (s < 256){
    float a = 0.f;
#pragma unroll
    for (int l = 0; l < NLAY; ++l) a += bsk[l*256 + s];
    bsum[s] = a;
  }
}
// zero the 512 guard rows of both h buffers (deterministic each call)
__global__ void k_zero_guard(short* __restrict__ hA, short* __restrict__ hB){
  int idx = blockIdx.x * 256 + threadIdx.x;
  if (idx < B_*512*128){
    int b = idx / (512*128);
    int rem = idx - b*(512*128);
    size_t off = (size_t)b*HROWS*128 + rem;
    hA[off] = 0; hB[off] = 0;
  }
}

// ---------------- head-in: h = 2*(w_pre0 @ shift(x,1) + b) -> swizzled bf16 hi/lo ----------------
__global__ __launch_bounds__(512) void k_head_in(
    const float* __restrict__ x, const short* __restrict__ wph,
    const short* __restrict__ wpl, const float* __restrict__ bias,
    short* __restrict__ h)
{
  __shared__ short SXh[64*256], SXl[64*256];
  const int tid = threadIdx.x;
  const int bb = blockIdx.x / NBT;
  const int t0 = (blockIdx.x % NBT) * 64;
  const int lane = tid & 63, w = tid >> 6;
  const int l16 = lane & 15, l4 = lane >> 4;

  const float* xb = x + (size_t)bb * 256 * T_;
  {
    int col = lane;
    int t = t0 + col - 1;
#pragma unroll
    for (int p = 0; p < 16; ++p){
      int k0 = w*32 + p*2;
      float v0 = (t >= 0) ? xb[(size_t)k0*T_ + t] : 0.f;
      float v1 = (t >= 0) ? xb[(size_t)(k0+1)*T_ + t] : 0.f;
      unsigned short h0,l0,h1,l1; split2(v0,h0,l0); split2(v1,h1,l1);
      int idx = col*256 + (k0 ^ ((col & 15) << 3));
      ((unsigned int*)SXh)[idx>>1] = (unsigned)h0 | ((unsigned)h1 << 16);
      ((unsigned int*)SXl)[idx>>1] = (unsigned)l0 | ((unsigned)l1 << 16);
    }
  }
  __syncthreads();

  const int mi = w & 3, nh = w >> 2;
  const int rowA = mi*16 + l16;
  const int rt0 = mi*16 + l4*4;
  bf16x8 Ah[8], Al[8];
#pragma unroll
  for (int kb = 0; kb < 8; ++kb){
    int ko = kb*32 + l4*8;
    Ah[kb] = *(const bf16x8*)(wph + (size_t)rowA*256 + ko);
    Al[kb] = *(const bf16x8*)(wpl + (size_t)rowA*256 + ko);
  }
  short* hb = h + ((size_t)bb*HROWS + 512)*128;
#pragma unroll
  for (int nt = 0; nt < 2; ++nt){
    int col = (nh*2 + nt)*16 + l16;
    f32x4 acc = {0.f,0.f,0.f,0.f};
#pragma unroll
    for (int kb = 0; kb < 8; ++kb){
      int ko = (kb*32 + l4*8) ^ (l16 << 3);
      bf16x8 bhv = *(const bf16x8*)&SXh[col*256 + ko];
      bf16x8 blv = *(const bf16x8*)&SXl[col*256 + ko];
      acc = MFMA(Ah[kb], bhv, acc);
      acc = MFMA(Ah[kb], blv, acc);
      acc = MFMA(Al[kb], bhv, acc);
    }
    int t = t0 + col;
    int key = t & 15;
    int c  = rt0 >> 3, sub = rt0 & 7;
    sh4 hv, lv;
#pragma unroll
    for (int r = 0; r < 4; ++r){
      float v = 2.f*(acc[r] + bias[rt0 + r]);
      unsigned short hh, ll; split2(v, hh, ll);
      hv[r] = (short)hh; lv[r] = (short)ll;
    }
    *(sh4*)&hb[(size_t)t*128 + ((c ^ key) << 3) + sub] = hv;
    *(sh4*)&hb[(size_t)t*128 + (((c + 8) ^ key) << 3) + sub] = lv;
  }
}

// ---------------- per-layer kernel v6 (R16, current best) ----------------
__global__ __launch_bounds__(512, 6) void k_layer6(
    const short* __restrict__ hin, short* __restrict__ hout,
    short* __restrict__ gout,     // per-layer base, tile-major [b][tile][4096] fragment order
    const short* __restrict__ wgh, const short* __restrict__ wgl,
    const short* __restrict__ wrh, const short* __restrict__ wrlo,
    const float* __restrict__ bh, const float* __restrict__ br, int d)
{
  __shared__ short SH[64*128];     // cur h rows (16KB)
  __shared__ short SHP[64*128];    // shifted h rows (16KB); SG overlay after gate
  const int tid = threadIdx.x;
  const int bb = blockIdx.x / NBT;
  const int tile = blockIdx.x % NBT;
  const int t0 = tile * 64;
  const int lane = tid & 63, w = tid >> 6;
  const int l16 = lane & 15, l4 = lane >> 4;

  const short* hb = hin + ((size_t)bb*HROWS + 512)*128;
  // async stage: wave w covers col quads 2w, 2w+1 for both tiles
  {
#pragma unroll
    for (int i = 0; i < 2; ++i){
      int colb = (w*2 + i)*4;
      const short* s1 = hb + (size_t)(t0 + colb + (lane>>4))*128 + (lane&15)*8;
      gload16(s1, &SH[colb*128]);
      const short* s2 = hb + (size_t)(t0 - d + colb + (lane>>4))*128 + (lane&15)*8;
      gload16(s2, &SHP[colb*128]);
    }
  }

  const int mi = w & 3, nh = w >> 2;
  const int rt0 = mi*16 + l4*4;
  const int rowt = mi*16 + l16, rows = 64 + mi*16 + l16;
  float bt[4], bs[4];
#pragma unroll
  for (int r = 0; r < 4; ++r){ bt[r] = bh[rt0+r]; bs[r] = bh[64+rt0+r]; }
  __syncthreads();   // drains global_load_lds (vmcnt0) + barrier

  // gate phase, K-grouped (per-accumulator MFMA order kb0,kb1,kb2,kb3 preserved)
  f32x4 at0 = {0.f,0.f,0.f,0.f}, at1 = {0.f,0.f,0.f,0.f};
  f32x4 as0 = {0.f,0.f,0.f,0.f}, as1 = {0.f,0.f,0.f,0.f};
  {  // group A: kb 0,1 -> SHP
#pragma unroll
    for (int kb = 0; kb < 2; ++kb){
      int ko = kb*32 + l4*8;
      bf16x8 Wth = *(const bf16x8*)(wgh + (size_t)rowt*128 + ko);
      bf16x8 Wtl = *(const bf16x8*)(wgl + (size_t)rowt*128 + ko);
      bf16x8 Wsh = *(const bf16x8*)(wgh + (size_t)rows*128 + ko);
      bf16x8 Wsl = *(const bf16x8*)(wgl + (size_t)rows*128 + ko);
      int cb = kb*4 + l4;
#pragma unroll
      for (int nt = 0; nt < 2; ++nt){
        int col = (nh*2 + nt)*16 + l16;
        int keyP = (col - d) & 15;
        bf16x8 bhv = *(const bf16x8*)&SHP[col*128 + ((cb ^ keyP) << 3)];
        bf16x8 blv = *(const bf16x8*)&SHP[col*128 + (((cb + 8) ^ keyP) << 3)];
        if (nt == 0){
          at0 = MFMA(Wth, bhv, at0); at0 = MFMA(Wth, blv, at0); at0 = MFMA(Wtl, bhv, at0);
          as0 = MFMA(Wsh, bhv, as0); as0 = MFMA(Wsh, blv, as0); as0 = MFMA(Wsl, bhv, as0);
        } else {
          at1 = MFMA(Wth, bhv, at1); at1 = MFMA(Wth, blv, at1); at1 = MFMA(Wtl, bhv, at1);
          as1 = MFMA(Wsh, bhv, as1); as1 = MFMA(Wsh, blv, as1); as1 = MFMA(Wsl, bhv, as1);
        }
      }
    }
  }
  {  // group B: kb 2,3 -> SH
#pragma unroll
    for (int kb = 2; kb < 4; ++kb){
      int ko = kb*32 + l4*8;
      bf16x8 Wth = *(const bf16x8*)(wgh + (size_t)rowt*128 + ko);
      bf16x8 Wtl = *(const bf16x8*)(wgl + (size_t)rowt*128 + ko);
      bf16x8 Wsh = *(const bf16x8*)(wgh + (size_t)rows*128 + ko);
      bf16x8 Wsl = *(const bf16x8*)(wgl + (size_t)rows*128 + ko);
      int cb = (kb & 1)*4 + l4;
#pragma unroll
      for (int nt = 0; nt < 2; ++nt){
        int col = (nh*2 + nt)*16 + l16;
        int keyC = col & 15;
        bf16x8 bhv = *(const bf16x8*)&SH[col*128 + ((cb ^ keyC) << 3)];
        bf16x8 blv = *(const bf16x8*)&SH[col*128 + (((cb + 8) ^ keyC) << 3)];
        if (nt == 0){
          at0 = MFMA(Wth, bhv, at0); at0 = MFMA(Wth, blv, at0); at0 = MFMA(Wtl, bhv, at0);
          as0 = MFMA(Wsh, bhv, as0); as0 = MFMA(Wsh, blv, as0); as0 = MFMA(Wsl, bhv, as0);
        } else {
          at1 = MFMA(Wth, bhv, at1); at1 = MFMA(Wth, blv, at1); at1 = MFMA(Wtl, bhv, at1);
          as1 = MFMA(Wsh, bhv, as1); as1 = MFMA(Wsh, blv, as1); as1 = MFMA(Wsl, bhv, as1);
        }
      }
    }
  }

  // nonlinearity -> packed g regs (hi/lo, 8 dwords)
  unsigned gp[2][4];
#pragma unroll
  for (int nt = 0; nt < 2; ++nt){
    unsigned short gh4[4], gl4[4];
#pragma unroll
    for (int r = 0; r < 4; ++r){
      float av = ((nt == 0) ? at0[r] : at1[r]) + bt[r];
      float sv = ((nt == 0) ? as0[r] : as1[r]) + bs[r];
      float e2 = __expf(2.f*av);
      float tv = 1.f - 2.f/(e2 + 1.f);
      float sg = 1.f/(1.f + __expf(-sv));
      float g  = tv*sg;
      split2(g, gh4[r], gl4[r]);
    }
    gp[nt][0] = (unsigned)gh4[0] | ((unsigned)gh4[1] << 16);
    gp[nt][1] = (unsigned)gh4[2] | ((unsigned)gh4[3] << 16);
    gp[nt][2] = (unsigned)gl4[0] | ((unsigned)gl4[1] << 16);
    gp[nt][3] = (unsigned)gl4[2] | ((unsigned)gl4[3] << 16);
  }
  __syncthreads();   // everyone done reading SHP

  short* SGh = SHP;          // overlay
  short* SGl = SHP + 4096;
#pragma unroll
  for (int nt = 0; nt < 2; ++nt){
    int col = (nh*2 + nt)*16 + l16;
    int gib = col*64 + (rt0 ^ ((col & 7) << 3));   // rt0+r consecutive under this XOR
    ((unsigned int*)&SGh[gib])[0] = gp[nt][0];
    ((unsigned int*)&SGh[gib])[1] = gp[nt][1];
    ((unsigned int*)&SGl[gib])[0] = gp[nt][2];
    ((unsigned int*)&SGl[gib])[1] = gp[nt][3];
  }
  __syncthreads();

  // bulk g store: fragment-major tile, 16B/thread fully coalesced.
  {
    int f = tid >> 6, j = tid & 63;
    int row = (f >> 1)*16 + (j & 15);
    int c   = (f & 1)*4 + (j >> 4);
    bf16x8 v = *(const bf16x8*)&SGh[row*64 + ((c ^ (row & 7)) << 3)];
    *(bf16x8*)(gout + ((size_t)bb*NBT + tile)*4096 + tid*8) = v;
  }

  // res phase: h_out = h_in + w_res@g + br
  {
    const int rowA = mi*16 + l16;
    bf16x8 Rh[2], Rl[2];
#pragma unroll
    for (int kb = 0; kb < 2; ++kb){
      int ko = kb*32 + l4*8;
      Rh[kb] = *(const bf16x8*)(wrh  + (size_t)rowA*64 + ko);
      Rl[kb] = *(const bf16x8*)(wrlo + (size_t)rowA*64 + ko);
    }
    short* ho = hout + ((size_t)bb*HROWS + 512)*128;
    const int cH = rt0 >> 3, sub = rt0 & 7;
#pragma unroll
    for (int nt = 0; nt < 2; ++nt){
      int col = (nh*2 + nt)*16 + l16;
      int keyC = col & 15;
      f32x4 acc = {0.f,0.f,0.f,0.f};
#pragma unroll
      for (int kb = 0; kb < 2; ++kb){
        int ko = (kb*32 + l4*8) ^ ((col & 7) << 3);
        bf16x8 bhv = *(const bf16x8*)&SGh[col*64 + ko];
        bf16x8 blv = *(const bf16x8*)&SGl[col*64 + ko];
        acc = MFMA(Rh[kb], bhv, acc);
        acc = MFMA(Rh[kb], blv, acc);
        acc = MFMA(Rl[kb], bhv, acc);
      }
      sh4 hi4 = *(const sh4*)&SH[col*128 + ((cH ^ keyC) << 3) + sub];
      sh4 lo4 = *(const sh4*)&SH[col*128 + (((cH + 8) ^ keyC) << 3) + sub];
      int t = t0 + col;
      sh4 hv, lv;
#pragma unroll
      for (int r = 0; r < 4; ++r){
        float hin_f = bf2f((unsigned short)hi4[r]) + bf2f((unsigned short)lo4[r]);
        float v = hin_f + acc[r] + br[rt0 + r];
        unsigned short hh, ll; split2(v, hh, ll);
        hv[r] = (short)hh; lv[r] = (short)ll;
      }
      *(sh4*)&ho[(size_t)t*128 + ((cH ^ keyC) << 3) + sub] = hv;
      *(sh4*)&ho[(size_t)t*128 + (((cH + 8) ^ keyC) << 3) + sub] = lv;
    }
  }
}

// ---------------- fused head v2: register-B barrier-free skip GEMM ----------------
// Wave w = (rh = w>>2, ntw = w&3): output rows [rh*128,+128) x cols [ntw*16,+16).
// B fragments loaded straight to VGPRs (no LDS, no barriers, no async staging).
__global__ __launch_bounds__(512) void k_head_fused(
    float* __restrict__ io,
    const short* __restrict__ g,                // [l][b][tile][4096] fragment-major
    const short* __restrict__ wsf,              // packed skip weights [l][w8][half][kb2][64][8]
    const float* __restrict__ bsum,
    const short* __restrict__ wrlh, const short* __restrict__ wrll,
    const float* __restrict__ brl,
    const short* __restrict__ woh, const short* __restrict__ wol,
    const float* __restrict__ bo)
{
  __shared__ short S1h[64*256];    // 32KB; reused for smax/ssum at the end
  const int tid = threadIdx.x;
  const int bb = blockIdx.x / NBT;
  const int tile = blockIdx.x % NBT;
  const int t0 = tile * 64;
  const int lane = tid & 63, w = tid >> 6;
  const int l16 = lane & 15, l4 = lane >> 4;

  const int r0 = w*32 + l16, r1 = w*32 + 16 + l16;
  const int rtb0 = w*32 + l4*4, rtb1 = rtb0 + 16;

  // ---- skip GEMM: per-wave rows/cols, B direct to registers, zero barriers ----
  const int rh = w >> 2, ntw = w & 3;
  f32x4 acc[8];
#pragma unroll
  for (int m = 0; m < 8; ++m) acc[m] = (f32x4){0.f,0.f,0.f,0.f};
  {
    const size_t LSTR = (size_t)B_ * NBT * 4096;
    const short* gfrag = g + ((size_t)bb*NBT + tile)*4096 + (ntw*2)*512 + lane*8;
    const short* wbase = wsf + (size_t)rh*4*2048 + lane*8;
    for (int l20 = 0; l20 < 20; ++l20){
      bf16x8 B0 = *(const bf16x8*)(gfrag + (size_t)l20*LSTR);
      bf16x8 B1 = *(const bf16x8*)(gfrag + (size_t)l20*LSTR + 512);
      const short* wl = wbase + (size_t)l20*16384;
#pragma unroll
      for (int m = 0; m < 8; ++m){
        const short* wm = wl + (m >> 1)*2048 + (m & 1)*1024;
        bf16x8 A0 = *(const bf16x8*)(wm);
        bf16x8 A1 = *(const bf16x8*)(wm + 512);
        acc[m] = MFMA(A0, B0, acc[m]);
        acc[m] = MFMA(A1, B1, acc[m]);
      }
    }
  }

  // bias + relu -> S1h (hi only), packed dword writes
  {
    const int c2 = ntw*16 + l16;
#pragma unroll
    for (int m = 0; m < 8; ++m){
      int rtb = rh*128 + m*16 + l4*4;
      unsigned short h[4];
#pragma unroll
      for (int r = 0; r < 4; ++r)
        h[r] = f2bf(fmaxf(acc[m][r] + bsum[rtb + r], 0.f));
      int i0 = c2*256 + (rtb ^ (l16 << 3));
      ((unsigned int*)&S1h[i0])[0] = (unsigned)h[0] | ((unsigned)h[1] << 16);
      ((unsigned int*)&S1h[i0])[1] = (unsigned)h[2] | ((unsigned)h[3] << 16);
    }
  }
  __syncthreads();

  f32x4 acc0[4], acc1[4];
  // GEMM1: o = wrl @ s1  (weight hi/lo x activation hi)
#pragma unroll
  for (int nt = 0; nt < 4; ++nt){ acc0[nt] = (f32x4){0.f,0.f,0.f,0.f}; acc1[nt] = (f32x4){0.f,0.f,0.f,0.f}; }
#pragma unroll
  for (int kb = 0; kb < 8; ++kb){
    int ko = kb*32 + l4*8;
    bf16x8 A0h = *(const bf16x8*)(wrlh + (size_t)r0*256 + ko);
    bf16x8 A0l = *(const bf16x8*)(wrll + (size_t)r0*256 + ko);
    bf16x8 A1h = *(const bf16x8*)(wrlh + (size_t)r1*256 + ko);
    bf16x8 A1l = *(const bf16x8*)(wrll + (size_t)r1*256 + ko);
#pragma unroll
    for (int nt = 0; nt < 4; ++nt){
      int c2 = nt*16 + l16;
      int kos = ko ^ (l16 << 3);
      bf16x8 bhv = *(const bf16x8*)&S1h[c2*256 + kos];
      acc0[nt] = MFMA(A0h, bhv, acc0[nt]);
      acc0[nt] = MFMA(A0l, bhv, acc0[nt]);
      acc1[nt] = MFMA(A1h, bhv, acc1[nt]);
      acc1[nt] = MFMA(A1l, bhv, acc1[nt]);
    }
  }
  __syncthreads();
  // relu + repack into S1h
  {
    float br0[4], br1[4];
#pragma unroll
    for (int r = 0; r < 4; ++r){ br0[r] = brl[rtb0+r]; br1[r] = brl[rtb1+r]; }
#pragma unroll
    for (int nt = 0; nt < 4; ++nt){
      int c2 = nt*16 + l16;
      unsigned short h[4];
#pragma unroll
      for (int r = 0; r < 4; ++r)
        h[r] = f2bf(fmaxf(acc0[nt][r] + br0[r], 0.f));
      int i0 = c2*256 + (rtb0 ^ (l16 << 3));
      ((unsigned int*)&S1h[i0])[0] = (unsigned)h[0] | ((unsigned)h[1] << 16);
      ((unsigned int*)&S1h[i0])[1] = (unsigned)h[2] | ((unsigned)h[3] << 16);
#pragma unroll
      for (int r = 0; r < 4; ++r)
        h[r] = f2bf(fmaxf(acc1[nt][r] + br1[r], 0.f));
      int i1 = c2*256 + (rtb1 ^ (l16 << 3));
      ((unsigned int*)&S1h[i1])[0] = (unsigned)h[0] | ((unsigned)h[1] << 16);
      ((unsigned int*)&S1h[i1])[1] = (unsigned)h[2] | ((unsigned)h[3] << 16);
    }
  }
  __syncthreads();

  // GEMM2: logits (weight hi/lo x activation hi)
#pragma unroll
  for (int nt = 0; nt < 4; ++nt){ acc0[nt] = (f32x4){0.f,0.f,0.f,0.f}; acc1[nt] = (f32x4){0.f,0.f,0.f,0.f}; }
#pragma unroll
  for (int kb = 0; kb < 8; ++kb){
    int ko = kb*32 + l4*8;
    bf16x8 A0h = *(const bf16x8*)(woh + (size_t)r0*256 + ko);
    bf16x8 A0l = *(const bf16x8*)(wol + (size_t)r0*256 + ko);
    bf16x8 A1h = *(const bf16x8*)(woh + (size_t)r1*256 + ko);
    bf16x8 A1l = *(const bf16x8*)(wol + (size_t)r1*256 + ko);
#pragma unroll
    for (int nt = 0; nt < 4; ++nt){
      int c2 = nt*16 + l16;
      int kos = ko ^ (l16 << 3);
      bf16x8 bhv = *(const bf16x8*)&S1h[c2*256 + kos];
      acc0[nt] = MFMA(A0h, bhv, acc0[nt]);
      acc0[nt] = MFMA(A0l, bhv, acc0[nt]);
      acc1[nt] = MFMA(A1h, bhv, acc1[nt]);
      acc1[nt] = MFMA(A1l, bhv, acc1[nt]);
    }
  }
  __syncthreads();   // S1h reads done before smax/ssum overlay reuse
  float* smax = (float*)S1h;              // [8][64]
  float* ssum = smax + 512;               // [8][64]
  float* iob = io + (size_t)bb * 256 * T_;
  float bo0[4], bo1[4];
#pragma unroll
  for (int r = 0; r < 4; ++r){ bo0[r] = bo[rtb0+r]; bo1[r] = bo[rtb1+r]; }
#pragma unroll
  for (int nt = 0; nt < 4; ++nt){
    float m = -1e30f;
#pragma unroll
    for (int r = 0; r < 4; ++r){
      acc0[nt][r] += bo0[r];
      acc1[nt][r] += bo1[r];
      m = fmaxf(m, fmaxf(acc0[nt][r], acc1[nt][r]));
    }
    m = fmaxf(m, __shfl_xor(m, 16, 64));
    m = fmaxf(m, __shfl_xor(m, 32, 64));
    smax[w*64 + nt*16 + l16] = m;
  }
  __syncthreads();
#pragma unroll
  for (int nt = 0; nt < 4; ++nt){
    float m = smax[nt*16 + l16];
#pragma unroll
    for (int ww = 1; ww < 8; ++ww) m = fmaxf(m, smax[ww*64 + nt*16 + l16]);
    float s = 0.f;
#pragma unroll
    for (int r = 0; r < 4; ++r){
      acc0[nt][r] = __expf(acc0[nt][r] - m); s += acc0[nt][r];
      acc1[nt][r] = __expf(acc1[nt][r] - m); s += acc1[nt][r];
    }
    s += __shfl_xor(s, 16, 64);
    s += __shfl_xor(s, 32, 64);
    ssum[w*64 + nt*16 + l16] = s;
  }
  __syncthreads();
#pragma unroll
  for (int nt = 0; nt < 4; ++nt){
    float S = 0.f;
#pragma unroll
    for (int ww = 0; ww < 8; ++ww) S += ssum[ww*64 + nt*16 + l16];
    float inv = 1.f / S;
    int t = t0 + nt*16 + l16;
#pragma unroll
    for (int r = 0; r < 4; ++r){
      iob[(size_t)(rtb0 + r)*T_ + t] = acc0[nt][r]*inv;
      iob[(size_t)(rtb1 + r)*T_ + t] = acc1[nt][r]*inv;
    }
  }
}

extern "C" void kernel_launch(void* const* d_in, const int* in_sizes, int n_in,
                              void* d_out, int out_size, void* d_ws, size_t ws_size,
                              hipStream_t stream) {
  const float* x       = (const float*)d_in[0];
  const float* w_pre0  = (const float*)d_in[1];
  const float* b_pre0  = (const float*)d_in[2];
  const float* w_dil_p = (const float*)d_in[3];
  const float* w_dil_c = (const float*)d_in[4];
  const float* bias_h  = (const float*)d_in[5];
  const float* w_res   = (const float*)d_in[6];
  const float* b_res   = (const float*)d_in[7];
  const float* w_skip  = (const float*)d_in[8];
  const float* b_skip  = (const float*)d_in[9];
  const float* w_relu  = (const float*)d_in[10];
  const float* b_relu  = (const float*)d_in[11];
  const float* w_out   = (const float*)d_in[12];
  const float* b_out   = (const float*)d_in[13];

  float* out = (float*)d_out;
  short* hA = (short*)d_ws;
  short* hB = hA + (size_t)B_ * HROWS * 128;
  float* bsum = (float*)(hB + (size_t)B_ * HROWS * 128);
  short* p   = (short*)(bsum + 256);
  short* WPh = p; p += 16384;  short* WPl = p; p += 16384;
  short* WGh = p; p += 327680; short* WGl = p; p += 327680;
  short* WRh = p; p += 81920;  short* WRl = p; p += 81920;
  short* WSF = p; p += 327680;
  short* WLh = p; p += 65536;  short* WLl = p; p += 65536;
  short* WOh = p; p += 65536;  short* WOl = p; p += 65536;
  short* GBUF = p;             // 20*8*250*4096 shorts = 327.68 MB

  // weight prep
  k_split<<<64, 256, 0, stream>>>(w_pre0, WPh, WPl, 16384);
  k_split_gate<<<1280, 256, 0, stream>>>(w_dil_p, w_dil_c, WGh, WGl);
  k_split<<<320, 256, 0, stream>>>(w_res, WRh, WRl, 81920);
  k_pack_wsf<<<1280, 256, 0, stream>>>(w_skip, WSF);
  k_split<<<256, 256, 0, stream>>>(w_relu, WLh, WLl, 65536);
  k_split<<<256, 256, 0, stream>>>(w_out, WOh, WOl, 65536);
  k_zero_guard<<<2048, 256, 0, stream>>>(hA, hB);
  k_bsum<<<1, 256, 0, stream>>>(b_skip, bsum);

  k_head_in<<<B_ * NBT, 512, 0, stream>>>(x, WPh, WPl, b_pre0, hA);

  const short* hin = hA;
  short* houtp = hB;
  for (int l = 0; l < NLAY; ++l) {
    int d = 1 << (l % 10);
    k_layer6<<<B_ * NBT, 512, 0, stream>>>(
        hin, houtp,
        GBUF + (size_t)l * B_ * NBT * 4096,
        WGh + (size_t)l*16384, WGl + (size_t)l*16384,
        WRh + (size_t)l*4096,  WRl + (size_t)l*4096,
        bias_h + (size_t)l*128, b_res + (size_t)l*64, d);
    const short* tmp = hin;
    hin = houtp;
    houtp = (short*)tmp;
  }

  k_head_fused<<<B_ * NBT, 512, 0, stream>>>(
      out, GBUF, WSF, bsum, WLh, WLl, b_relu, WOh, WOl, b_out);
}

// Round 19
// 1482.056 us; speedup vs baseline: 1.0083x; 1.0083x over previous
//
#include <hip/hip_runtime.h>
#include <math.h>

#define B_ 8
#define T_ 16000
#define NBT 250          // time-blocks of 64 cols
#define HROWS 16512      // 512 guard rows + 16000
#define NLAY 20

typedef __attribute__((ext_vector_type(8))) short bf16x8;
typedef __attribute__((ext_vector_type(4))) float f32x4;
typedef __attribute__((ext_vector_type(4))) short sh4;

__device__ __forceinline__ unsigned short f2bf(float f){
  unsigned u = __float_as_uint(f);
  u += 0x7fffu + ((u >> 16) & 1u);          // RNE to bf16
  return (unsigned short)(u >> 16);
}
__device__ __forceinline__ float bf2f(unsigned short s){
  return __uint_as_float(((unsigned)s) << 16);
}
__device__ __forceinline__ void split2(float v, unsigned short& hi, unsigned short& lo){
  hi = f2bf(v);
  lo = f2bf(v - bf2f(hi));
}

#define MFMA(a,b,c) __builtin_amdgcn_mfma_f32_16x16x32_bf16((a),(b),(c),0,0,0)

// async global->LDS 16B per lane (dest = uniform base + lane*16, src per-lane)
__device__ __forceinline__ void gload16(const short* gsrc, short* ldst){
  __builtin_amdgcn_global_load_lds(
      (const __attribute__((address_space(1))) unsigned int*)gsrc,
      (__attribute__((address_space(3))) unsigned int*)ldst, 16, 0, 0);
}
// 32-bit LDS byte address for inline-asm ds_read
__device__ __forceinline__ unsigned ldsaddr(const short* p){
  return (unsigned)(size_t)(const __attribute__((address_space(3))) short*)p;
}

// ---------------- prep kernels ----------------
__global__ void k_split(const float* __restrict__ src, short* __restrict__ hi,
                        short* __restrict__ lo, int n){
  int idx = blockIdx.x * 256 + threadIdx.x;
  if (idx < n){
    unsigned short h, l; split2(src[idx], h, l);
    hi[idx] = (short)h; lo[idx] = (short)l;
  }
}
// gate weights: Wg[l][row][k] : k<64 -> wdp[l][row][k], else wdc[l][row][k-64]
__global__ void k_split_gate(const float* __restrict__ wdp, const float* __restrict__ wdc,
                             short* __restrict__ hi, short* __restrict__ lo){
  int idx = blockIdx.x * 256 + threadIdx.x;
  if (idx < NLAY*128*128){
    int l   = idx >> 14;
    int rem = idx & 16383;
    int row = rem >> 7;
    int k   = rem & 127;
    float v = (k < 64) ? wdp[(l*128 + row)*64 + k] : wdc[(l*128 + row)*64 + (k-64)];
    unsigned short h, lo16; split2(v, h, lo16);
    hi[idx] = (short)h; lo[idx] = (short)lo16;
  }
}
// skip weights packed fragment-major: WSF[l][w][half][kb2][lane j][8]
__global__ void k_pack_wsf(const float* __restrict__ wsk, short* __restrict__ wsf){
  int idx = blockIdx.x * 256 + threadIdx.x;
  if (idx < NLAY*8*2*2*64*8){
    int e    = idx & 7;
    int j    = (idx >> 3) & 63;
    int kb2  = (idx >> 9) & 1;
    int half = (idx >> 10) & 1;
    int w    = (idx >> 11) & 7;
    int l    = idx >> 14;
    int row  = w*32 + half*16 + (j & 15);
    int ch   = (kb2*4 + (j >> 4))*8 + e;
    wsf[idx] = (short)f2bf(wsk[((size_t)l*256 + row)*64 + ch]);
  }
}
__global__ void k_bsum(const float* __restrict__ bsk, float* __restrict__ bsum){
  int s = threadIdx.x;
  if (s < 256){
    float a = 0.f;
#pragma unroll
    for (int l = 0; l < NLAY; ++l) a += bsk[l*256 + s];
    bsum[s] = a;
  }
}
// zero the 512 guard rows of both h buffers (deterministic each call)
__global__ void k_zero_guard(short* __restrict__ hA, short* __restrict__ hB){
  int idx = blockIdx.x * 256 + threadIdx.x;
  if (idx < B_*512*128){
    int b = idx / (512*128);
    int rem = idx - b*(512*128);
    size_t off = (size_t)b*HROWS*128 + rem;
    hA[off] = 0; hB[off] = 0;
  }
}

// ---------------- head-in: h = 2*(w_pre0 @ shift(x,1) + b) -> swizzled bf16 hi/lo ----------------
__global__ __launch_bounds__(512) void k_head_in(
    const float* __restrict__ x, const short* __restrict__ wph,
    const short* __restrict__ wpl, const float* __restrict__ bias,
    short* __restrict__ h)
{
  __shared__ short SXh[64*256], SXl[64*256];
  const int tid = threadIdx.x;
  const int bb = blockIdx.x / NBT;
  const int t0 = (blockIdx.x % NBT) * 64;
  const int lane = tid & 63, w = tid >> 6;
  const int l16 = lane & 15, l4 = lane >> 4;

  const float* xb = x + (size_t)bb * 256 * T_;
  {
    int col = lane;
    int t = t0 + col - 1;
#pragma unroll
    for (int p = 0; p < 16; ++p){
      int k0 = w*32 + p*2;
      float v0 = (t >= 0) ? xb[(size_t)k0*T_ + t] : 0.f;
      float v1 = (t >= 0) ? xb[(size_t)(k0+1)*T_ + t] : 0.f;
      unsigned short h0,l0,h1,l1; split2(v0,h0,l0); split2(v1,h1,l1);
      int idx = col*256 + (k0 ^ ((col & 15) << 3));
      ((unsigned int*)SXh)[idx>>1] = (unsigned)h0 | ((unsigned)h1 << 16);
      ((unsigned int*)SXl)[idx>>1] = (unsigned)l0 | ((unsigned)l1 << 16);
    }
  }
  __syncthreads();

  const int mi = w & 3, nh = w >> 2;
  const int rowA = mi*16 + l16;
  const int rt0 = mi*16 + l4*4;
  bf16x8 Ah[8], Al[8];
#pragma unroll
  for (int kb = 0; kb < 8; ++kb){
    int ko = kb*32 + l4*8;
    Ah[kb] = *(const bf16x8*)(wph + (size_t)rowA*256 + ko);
    Al[kb] = *(const bf16x8*)(wpl + (size_t)rowA*256 + ko);
  }
  short* hb = h + ((size_t)bb*HROWS + 512)*128;
#pragma unroll
  for (int nt = 0; nt < 2; ++nt){
    int col = (nh*2 + nt)*16 + l16;
    f32x4 acc = {0.f,0.f,0.f,0.f};
#pragma unroll
    for (int kb = 0; kb < 8; ++kb){
      int ko = (kb*32 + l4*8) ^ (l16 << 3);
      bf16x8 bhv = *(const bf16x8*)&SXh[col*256 + ko];
      bf16x8 blv = *(const bf16x8*)&SXl[col*256 + ko];
      acc = MFMA(Ah[kb], bhv, acc);
      acc = MFMA(Ah[kb], blv, acc);
      acc = MFMA(Al[kb], bhv, acc);
    }
    int t = t0 + col;
    int key = t & 15;
    int c  = rt0 >> 3, sub = rt0 & 7;
    sh4 hv, lv;
#pragma unroll
    for (int r = 0; r < 4; ++r){
      float v = 2.f*(acc[r] + bias[rt0 + r]);
      unsigned short hh, ll; split2(v, hh, ll);
      hv[r] = (short)hh; lv[r] = (short)ll;
    }
    *(sh4*)&hb[(size_t)t*128 + ((c ^ key) << 3) + sub] = hv;
    *(sh4*)&hb[(size_t)t*128 + (((c + 8) ^ key) << 3) + sub] = lv;
  }
}

// ---------------- per-layer kernel v6 (R16, current best) ----------------
__global__ __launch_bounds__(512, 6) void k_layer6(
    const short* __restrict__ hin, short* __restrict__ hout,
    short* __restrict__ gout,     // per-layer base, tile-major [b][tile][4096] fragment order
    const short* __restrict__ wgh, const short* __restrict__ wgl,
    const short* __restrict__ wrh, const short* __restrict__ wrlo,
    const float* __restrict__ bh, const float* __restrict__ br, int d)
{
  __shared__ short SH[64*128];     // cur h rows (16KB)
  __shared__ short SHP[64*128];    // shifted h rows (16KB); SG overlay after gate
  const int tid = threadIdx.x;
  const int bb = blockIdx.x / NBT;
  const int tile = blockIdx.x % NBT;
  const int t0 = tile * 64;
  const int lane = tid & 63, w = tid >> 6;
  const int l16 = lane & 15, l4 = lane >> 4;

  const short* hb = hin + ((size_t)bb*HROWS + 512)*128;
  // async stage: wave w covers col quads 2w, 2w+1 for both tiles
  {
#pragma unroll
    for (int i = 0; i < 2; ++i){
      int colb = (w*2 + i)*4;
      const short* s1 = hb + (size_t)(t0 + colb + (lane>>4))*128 + (lane&15)*8;
      gload16(s1, &SH[colb*128]);
      const short* s2 = hb + (size_t)(t0 - d + colb + (lane>>4))*128 + (lane&15)*8;
      gload16(s2, &SHP[colb*128]);
    }
  }

  const int mi = w & 3, nh = w >> 2;
  const int rt0 = mi*16 + l4*4;
  const int rowt = mi*16 + l16, rows = 64 + mi*16 + l16;
  float bt[4], bs[4];
#pragma unroll
  for (int r = 0; r < 4; ++r){ bt[r] = bh[rt0+r]; bs[r] = bh[64+rt0+r]; }
  __syncthreads();   // drains global_load_lds (vmcnt0) + barrier

  // gate phase, K-grouped (per-accumulator MFMA order kb0,kb1,kb2,kb3 preserved)
  f32x4 at0 = {0.f,0.f,0.f,0.f}, at1 = {0.f,0.f,0.f,0.f};
  f32x4 as0 = {0.f,0.f,0.f,0.f}, as1 = {0.f,0.f,0.f,0.f};
  {  // group A: kb 0,1 -> SHP
#pragma unroll
    for (int kb = 0; kb < 2; ++kb){
      int ko = kb*32 + l4*8;
      bf16x8 Wth = *(const bf16x8*)(wgh + (size_t)rowt*128 + ko);
      bf16x8 Wtl = *(const bf16x8*)(wgl + (size_t)rowt*128 + ko);
      bf16x8 Wsh = *(const bf16x8*)(wgh + (size_t)rows*128 + ko);
      bf16x8 Wsl = *(const bf16x8*)(wgl + (size_t)rows*128 + ko);
      int cb = kb*4 + l4;
#pragma unroll
      for (int nt = 0; nt < 2; ++nt){
        int col = (nh*2 + nt)*16 + l16;
        int keyP = (col - d) & 15;
        bf16x8 bhv = *(const bf16x8*)&SHP[col*128 + ((cb ^ keyP) << 3)];
        bf16x8 blv = *(const bf16x8*)&SHP[col*128 + (((cb + 8) ^ keyP) << 3)];
        if (nt == 0){
          at0 = MFMA(Wth, bhv, at0); at0 = MFMA(Wth, blv, at0); at0 = MFMA(Wtl, bhv, at0);
          as0 = MFMA(Wsh, bhv, as0); as0 = MFMA(Wsh, blv, as0); as0 = MFMA(Wsl, bhv, as0);
        } else {
          at1 = MFMA(Wth, bhv, at1); at1 = MFMA(Wth, blv, at1); at1 = MFMA(Wtl, bhv, at1);
          as1 = MFMA(Wsh, bhv, as1); as1 = MFMA(Wsh, blv, as1); as1 = MFMA(Wsl, bhv, as1);
        }
      }
    }
  }
  {  // group B: kb 2,3 -> SH
#pragma unroll
    for (int kb = 2; kb < 4; ++kb){
      int ko = kb*32 + l4*8;
      bf16x8 Wth = *(const bf16x8*)(wgh + (size_t)rowt*128 + ko);
      bf16x8 Wtl = *(const bf16x8*)(wgl + (size_t)rowt*128 + ko);
      bf16x8 Wsh = *(const bf16x8*)(wgh + (size_t)rows*128 + ko);
      bf16x8 Wsl = *(const bf16x8*)(wgl + (size_t)rows*128 + ko);
      int cb = (kb & 1)*4 + l4;
#pragma unroll
      for (int nt = 0; nt < 2; ++nt){
        int col = (nh*2 + nt)*16 + l16;
        int keyC = col & 15;
        bf16x8 bhv = *(const bf16x8*)&SH[col*128 + ((cb ^ keyC) << 3)];
        bf16x8 blv = *(const bf16x8*)&SH[col*128 + (((cb + 8) ^ keyC) << 3)];
        if (nt == 0){
          at0 = MFMA(Wth, bhv, at0); at0 = MFMA(Wth, blv, at0); at0 = MFMA(Wtl, bhv, at0);
          as0 = MFMA(Wsh, bhv, as0); as0 = MFMA(Wsh, blv, as0); as0 = MFMA(Wsl, bhv, as0);
        } else {
          at1 = MFMA(Wth, bhv, at1); at1 = MFMA(Wth, blv, at1); at1 = MFMA(Wtl, bhv, at1);
          as1 = MFMA(Wsh, bhv, as1); as1 = MFMA(Wsh, blv, as1); as1 = MFMA(Wsl, bhv, as1);
        }
      }
    }
  }

  // nonlinearity -> packed g regs (hi/lo, 8 dwords)
  unsigned gp[2][4];
#pragma unroll
  for (int nt = 0; nt < 2; ++nt){
    unsigned short gh4[4], gl4[4];
#pragma unroll
    for (int r = 0; r < 4; ++r){
      float av = ((nt == 0) ? at0[r] : at1[r]) + bt[r];
      float sv = ((nt == 0) ? as0[r] : as1[r]) + bs[r];
      float e2 = __expf(2.f*av);
      float tv = 1.f - 2.f/(e2 + 1.f);
      float sg = 1.f/(1.f + __expf(-sv));
      float g  = tv*sg;
      split2(g, gh4[r], gl4[r]);
    }
    gp[nt][0] = (unsigned)gh4[0] | ((unsigned)gh4[1] << 16);
    gp[nt][1] = (unsigned)gh4[2] | ((unsigned)gh4[3] << 16);
    gp[nt][2] = (unsigned)gl4[0] | ((unsigned)gl4[1] << 16);
    gp[nt][3] = (unsigned)gl4[2] | ((unsigned)gl4[3] << 16);
  }
  __syncthreads();   // everyone done reading SHP

  short* SGh = SHP;          // overlay
  short* SGl = SHP + 4096;
#pragma unroll
  for (int nt = 0; nt < 2; ++nt){
    int col = (nh*2 + nt)*16 + l16;
    int gib = col*64 + (rt0 ^ ((col & 7) << 3));   // rt0+r consecutive under this XOR
    ((unsigned int*)&SGh[gib])[0] = gp[nt][0];
    ((unsigned int*)&SGh[gib])[1] = gp[nt][1];
    ((unsigned int*)&SGl[gib])[0] = gp[nt][2];
    ((unsigned int*)&SGl[gib])[1] = gp[nt][3];
  }
  __syncthreads();

  // bulk g store: fragment-major tile, 16B/thread fully coalesced.
  {
    int f = tid >> 6, j = tid & 63;
    int row = (f >> 1)*16 + (j & 15);
    int c   = (f & 1)*4 + (j >> 4);
    bf16x8 v = *(const bf16x8*)&SGh[row*64 + ((c ^ (row & 7)) << 3)];
    *(bf16x8*)(gout + ((size_t)bb*NBT + tile)*4096 + tid*8) = v;
  }

  // res phase: h_out = h_in + w_res@g + br
  {
    const int rowA = mi*16 + l16;
    bf16x8 Rh[2], Rl[2];
#pragma unroll
    for (int kb = 0; kb < 2; ++kb){
      int ko = kb*32 + l4*8;
      Rh[kb] = *(const bf16x8*)(wrh  + (size_t)rowA*64 + ko);
      Rl[kb] = *(const bf16x8*)(wrlo + (size_t)rowA*64 + ko);
    }
    short* ho = hout + ((size_t)bb*HROWS + 512)*128;
    const int cH = rt0 >> 3, sub = rt0 & 7;
#pragma unroll
    for (int nt = 0; nt < 2; ++nt){
      int col = (nh*2 + nt)*16 + l16;
      int keyC = col & 15;
      f32x4 acc = {0.f,0.f,0.f,0.f};
#pragma unroll
      for (int kb = 0; kb < 2; ++kb){
        int ko = (kb*32 + l4*8) ^ ((col & 7) << 3);
        bf16x8 bhv = *(const bf16x8*)&SGh[col*64 + ko];
        bf16x8 blv = *(const bf16x8*)&SGl[col*64 + ko];
        acc = MFMA(Rh[kb], bhv, acc);
        acc = MFMA(Rh[kb], blv, acc);
        acc = MFMA(Rl[kb], bhv, acc);
      }
      sh4 hi4 = *(const sh4*)&SH[col*128 + ((cH ^ keyC) << 3) + sub];
      sh4 lo4 = *(const sh4*)&SH[col*128 + (((cH + 8) ^ keyC) << 3) + sub];
      int t = t0 + col;
      sh4 hv, lv;
#pragma unroll
      for (int r = 0; r < 4; ++r){
        float hin_f = bf2f((unsigned short)hi4[r]) + bf2f((unsigned short)lo4[r]);
        float v = hin_f + acc[r] + br[rt0 + r];
        unsigned short hh, ll; split2(v, hh, ll);
        hv[r] = (short)hh; lv[r] = (short)ll;
      }
      *(sh4*)&ho[(size_t)t*128 + ((cH ^ keyC) << 3) + sub] = hv;
      *(sh4*)&ho[(size_t)t*128 + (((cH + 8) ^ keyC) << 3) + sub] = lv;
    }
  }
}

// ---------------- fused head v4: barrier-free per-wave pipeline (ds_read addr FIXED: +lane*16) ----
__global__ __launch_bounds__(512) void k_head_fused(
    float* __restrict__ io,
    const short* __restrict__ g,                // [l][b][tile][4096] fragment-major
    const short* __restrict__ wsf,              // packed skip weights [l][w8][half][kb2][64][8]
    const float* __restrict__ bsum,
    const short* __restrict__ wrlh, const short* __restrict__ wrll,
    const float* __restrict__ brl,
    const short* __restrict__ woh, const short* __restrict__ wol,
    const float* __restrict__ bo)
{
  __shared__ short POOL[16384];    // skip loop: per-wave [w][buf][frag][512]; later S1h/smax
  const int tid = threadIdx.x;
  const int bb = blockIdx.x / NBT;
  const int tile = blockIdx.x % NBT;
  const int t0 = tile * 64;
  const int lane = tid & 63, w = tid >> 6;
  const int l16 = lane & 15, l4 = lane >> 4;

  const int r0 = w*32 + l16, r1 = w*32 + 16 + l16;
  const int rtb0 = w*32 + l4*4, rtb1 = rtb0 + 16;

  // ---- skip GEMM, barrier-free ----
  const int rh = w >> 2, ntw = w & 3;
  f32x4 acc[8];
#pragma unroll
  for (int m = 0; m < 8; ++m) acc[m] = (f32x4){0.f,0.f,0.f,0.f};
  {
    const size_t LSTR = (size_t)B_ * NBT * 4096;
    const short* gfrag = g + ((size_t)bb*NBT + tile)*4096 + (ntw*2)*512 + lane*8;
    const short* wbase = wsf + (size_t)rh*4*2048 + lane*8;
    short* myB = &POOL[w*2048];          // 4096 bytes private region
    const unsigned ba = ldsaddr(myB) + (unsigned)(lane * 16);   // per-lane 16B slot

#define STAGE2(l20, buf) do{ \
      gload16(gfrag + (size_t)(l20)*LSTR,        &myB[(buf)*1024]); \
      gload16(gfrag + (size_t)(l20)*LSTR + 512,  &myB[(buf)*1024 + 512]); }while(0)

    STAGE2(0, 0);
    for (int l20 = 0; l20 < 20; ++l20){
      // A-loads hoisted BEFORE next STAGE so vmcnt(2) leaves only prefetch in flight
      const short* wl = wbase + (size_t)l20*16384;
      bf16x8 A[8][2];
#pragma unroll
      for (int m = 0; m < 8; ++m){
        const short* wm = wl + (m >> 1)*2048 + (m & 1)*1024;
        A[m][0] = *(const bf16x8*)(wm);
        A[m][1] = *(const bf16x8*)(wm + 512);
      }
      if (l20 + 1 < 20){
        STAGE2(l20 + 1, (l20 + 1) & 1);
        asm volatile("s_waitcnt vmcnt(2)" ::: "memory");
      } else {
        asm volatile("s_waitcnt vmcnt(0)" ::: "memory");
      }
      // B-read via asm ds_read, per-lane address, early-clobber outputs
      bf16x8 B0, B1;
      unsigned a0 = ba + (unsigned)((l20 & 1) * 2048);
      asm volatile("ds_read_b128 %0, %1" : "=&v"(B0) : "v"(a0) : "memory");
      asm volatile("ds_read_b128 %0, %1 offset:1024" : "=&v"(B1) : "v"(a0) : "memory");
      asm volatile("s_waitcnt lgkmcnt(0)" ::: "memory");
      __builtin_amdgcn_sched_barrier(0);
      __builtin_amdgcn_s_setprio(1);
#pragma unroll
      for (int m = 0; m < 8; ++m){
        acc[m] = MFMA(A[m][0], B0, acc[m]);
        acc[m] = MFMA(A[m][1], B1, acc[m]);
      }
      __builtin_amdgcn_s_setprio(0);
      __builtin_amdgcn_sched_barrier(0);
    }
#undef STAGE2
  }
  __syncthreads();   // all waves done with private regions before S1h overlay

  short* S1h = POOL;
  // bias + relu -> S1h (hi only), packed dword writes
  {
    const int c2 = ntw*16 + l16;
#pragma unroll
    for (int m = 0; m < 8; ++m){
      int rtb = rh*128 + m*16 + l4*4;
      unsigned short h[4];
#pragma unroll
      for (int r = 0; r < 4; ++r)
        h[r] = f2bf(fmaxf(acc[m][r] + bsum[rtb + r], 0.f));
      int i0 = c2*256 + (rtb ^ (l16 << 3));
      ((unsigned int*)&S1h[i0])[0] = (unsigned)h[0] | ((unsigned)h[1] << 16);
      ((unsigned int*)&S1h[i0])[1] = (unsigned)h[2] | ((unsigned)h[3] << 16);
    }
  }
  __syncthreads();

  f32x4 acc0[4], acc1[4];
  // GEMM1: o = wrl @ s1  (weight hi/lo x activation hi)
#pragma unroll
  for (int nt = 0; nt < 4; ++nt){ acc0[nt] = (f32x4){0.f,0.f,0.f,0.f}; acc1[nt] = (f32x4){0.f,0.f,0.f,0.f}; }
#pragma unroll
  for (int kb = 0; kb < 8; ++kb){
    int ko = kb*32 + l4*8;
    bf16x8 A0h = *(const bf16x8*)(wrlh + (size_t)r0*256 + ko);
    bf16x8 A0l = *(const bf16x8*)(wrll + (size_t)r0*256 + ko);
    bf16x8 A1h = *(const bf16x8*)(wrlh + (size_t)r1*256 + ko);
    bf16x8 A1l = *(const bf16x8*)(wrll + (size_t)r1*256 + ko);
#pragma unroll
    for (int nt = 0; nt < 4; ++nt){
      int c2 = nt*16 + l16;
      int kos = ko ^ (l16 << 3);
      bf16x8 bhv = *(const bf16x8*)&S1h[c2*256 + kos];
      acc0[nt] = MFMA(A0h, bhv, acc0[nt]);
      acc0[nt] = MFMA(A0l, bhv, acc0[nt]);
      acc1[nt] = MFMA(A1h, bhv, acc1[nt]);
      acc1[nt] = MFMA(A1l, bhv, acc1[nt]);
    }
  }
  __syncthreads();
  // relu + repack into S1h
  {
    float br0[4], br1[4];
#pragma unroll
    for (int r = 0; r < 4; ++r){ br0[r] = brl[rtb0+r]; br1[r] = brl[rtb1+r]; }
#pragma unroll
    for (int nt = 0; nt < 4; ++nt){
      int c2 = nt*16 + l16;
      unsigned short h[4];
#pragma unroll
      for (int r = 0; r < 4; ++r)
        h[r] = f2bf(fmaxf(acc0[nt][r] + br0[r], 0.f));
      int i0 = c2*256 + (rtb0 ^ (l16 << 3));
      ((unsigned int*)&S1h[i0])[0] = (unsigned)h[0] | ((unsigned)h[1] << 16);
      ((unsigned int*)&S1h[i0])[1] = (unsigned)h[2] | ((unsigned)h[3] << 16);
#pragma unroll
      for (int r = 0; r < 4; ++r)
        h[r] = f2bf(fmaxf(acc1[nt][r] + br1[r], 0.f));
      int i1 = c2*256 + (rtb1 ^ (l16 << 3));
      ((unsigned int*)&S1h[i1])[0] = (unsigned)h[0] | ((unsigned)h[1] << 16);
      ((unsigned int*)&S1h[i1])[1] = (unsigned)h[2] | ((unsigned)h[3] << 16);
    }
  }
  __syncthreads();

  // GEMM2: logits (weight hi/lo x activation hi)
#pragma unroll
  for (int nt = 0; nt < 4; ++nt){ acc0[nt] = (f32x4){0.f,0.f,0.f,0.f}; acc1[nt] = (f32x4){0.f,0.f,0.f,0.f}; }
#pragma unroll
  for (int kb = 0; kb < 8; ++kb){
    int ko = kb*32 + l4*8;
    bf16x8 A0h = *(const bf16x8*)(woh + (size_t)r0*256 + ko);
    bf16x8 A0l = *(const bf16x8*)(wol + (size_t)r0*256 + ko);
    bf16x8 A1h = *(const bf16x8*)(woh + (size_t)r1*256 + ko);
    bf16x8 A1l = *(const bf16x8*)(wol + (size_t)r1*256 + ko);
#pragma unroll
    for (int nt = 0; nt < 4; ++nt){
      int c2 = nt*16 + l16;
      int kos = ko ^ (l16 << 3);
      bf16x8 bhv = *(const bf16x8*)&S1h[c2*256 + kos];
      acc0[nt] = MFMA(A0h, bhv, acc0[nt]);
      acc0[nt] = MFMA(A0l, bhv, acc0[nt]);
      acc1[nt] = MFMA(A1h, bhv, acc1[nt]);
      acc1[nt] = MFMA(A1l, bhv, acc1[nt]);
    }
  }
  __syncthreads();   // S1h reads done before smax/ssum overlay reuse
  float* smax = (float*)POOL;             // [8][64]
  float* ssum = smax + 512;               // [8][64]
  float* iob = io + (size_t)bb * 256 * T_;
  float bo0[4], bo1[4];
#pragma unroll
  for (int r = 0; r < 4; ++r){ bo0[r] = bo[rtb0+r]; bo1[r] = bo[rtb1+r]; }
#pragma unroll
  for (int nt = 0; nt < 4; ++nt){
    float m = -1e30f;
#pragma unroll
    for (int r = 0; r < 4; ++r){
      acc0[nt][r] += bo0[r];
      acc1[nt][r] += bo1[r];
      m = fmaxf(m, fmaxf(acc0[nt][r], acc1[nt][r]));
    }
    m = fmaxf(m, __shfl_xor(m, 16, 64));
    m = fmaxf(m, __shfl_xor(m, 32, 64));
    smax[w*64 + nt*16 + l16] = m;
  }
  __syncthreads();
#pragma unroll
  for (int nt = 0; nt < 4; ++nt){
    float m = smax[nt*16 + l16];
#pragma unroll
    for (int ww = 1; ww < 8; ++ww) m = fmaxf(m, smax[ww*64 + nt*16 + l16]);
    float s = 0.f;
#pragma unroll
    for (int r = 0; r < 4; ++r){
      acc0[nt][r] = __expf(acc0[nt][r] - m); s += acc0[nt][r];
      acc1[nt][r] = __expf(acc1[nt][r] - m); s += acc1[nt][r];
    }
    s += __shfl_xor(s, 16, 64);
    s += __shfl_xor(s, 32, 64);
    ssum[w*64 + nt*16 + l16] = s;
  }
  __syncthreads();
#pragma unroll
  for (int nt = 0; nt < 4; ++nt){
    float S = 0.f;
#pragma unroll
    for (int ww = 0; ww < 8; ++ww) S += ssum[ww*64 + nt*16 + l16];
    float inv = 1.f / S;
    int t = t0 + nt*16 + l16;
#pragma unroll
    for (int r = 0; r < 4; ++r){
      iob[(size_t)(rtb0 + r)*T_ + t] = acc0[nt][r]*inv;
      iob[(size_t)(rtb1 + r)*T_ + t] = acc1[nt][r]*inv;
    }
  }
}

extern "C" void kernel_launch(void* const* d_in, const int* in_sizes, int n_in,
                              void* d_out, int out_size, void* d_ws, size_t ws_size,
                              hipStream_t stream) {
  const float* x       = (const float*)d_in[0];
  const float* w_pre0  = (const float*)d_in[1];
  const float* b_pre0  = (const float*)d_in[2];
  const float* w_dil_p = (const float*)d_in[3];
  const float* w_dil_c = (const float*)d_in[4];
  const float* bias_h  = (const float*)d_in[5];
  const float* w_res   = (const float*)d_in[6];
  const float* b_res   = (const float*)d_in[7];
  const float* w_skip  = (const float*)d_in[8];
  const float* b_skip  = (const float*)d_in[9];
  const float* w_relu  = (const float*)d_in[10];
  const float* b_relu  = (const float*)d_in[11];
  const float* w_out   = (const float*)d_in[12];
  const float* b_out   = (const float*)d_in[13];

  float* out = (float*)d_out;
  short* hA = (short*)d_ws;
  short* hB = hA + (size_t)B_ * HROWS * 128;
  float* bsum = (float*)(hB + (size_t)B_ * HROWS * 128);
  short* p   = (short*)(bsum + 256);
  short* WPh = p; p += 16384;  short* WPl = p; p += 16384;
  short* WGh = p; p += 327680; short* WGl = p; p += 327680;
  short* WRh = p; p += 81920;  short* WRl = p; p += 81920;
  short* WSF = p; p += 327680;
  short* WLh = p; p += 65536;  short* WLl = p; p += 65536;
  short* WOh = p; p += 65536;  short* WOl = p; p += 65536;
  short* GBUF = p;             // 20*8*250*4096 shorts = 327.68 MB

  // weight prep
  k_split<<<64, 256, 0, stream>>>(w_pre0, WPh, WPl, 16384);
  k_split_gate<<<1280, 256, 0, stream>>>(w_dil_p, w_dil_c, WGh, WGl);
  k_split<<<320, 256, 0, stream>>>(w_res, WRh, WRl, 81920);
  k_pack_wsf<<<1280, 256, 0, stream>>>(w_skip, WSF);
  k_split<<<256, 256, 0, stream>>>(w_relu, WLh, WLl, 65536);
  k_split<<<256, 256, 0, stream>>>(w_out, WOh, WOl, 65536);
  k_zero_guard<<<2048, 256, 0, stream>>>(hA, hB);
  k_bsum<<<1, 256, 0, stream>>>(b_skip, bsum);

  k_head_in<<<B_ * NBT, 512, 0, stream>>>(x, WPh, WPl, b_pre0, hA);

  const short* hin = hA;
  short* houtp = hB;
  for (int l = 0; l < NLAY; ++l) {
    int d = 1 << (l % 10);
    k_layer6<<<B_ * NBT, 512, 0, stream>>>(
        hin, houtp,
        GBUF + (size_t)l * B_ * NBT * 4096,
        WGh + (size_t)l*16384, WGl + (size_t)l*16384,
        WRh + (size_t)l*4096,  WRl + (size_t)l*4096,
        bias_h + (size_t)l*128, b_res + (size_t)l*64, d);
    const short* tmp = hin;
    hin = houtp;
    houtp = (short*)tmp;
  }

  k_head_fused<<<B_ * NBT, 512, 0, stream>>>(
      out, GBUF, WSF, bsum, WLh, WLl, b_relu, WOh, WOl, b_out);
}

// Round 20
// 1326.497 us; speedup vs baseline: 1.1265x; 1.1173x over previous
//
#include <hip/hip_runtime.h>
#include <math.h>

#define B_ 8
#define T_ 16000
#define NBT 250          // time-blocks of 64 cols
#define HROWS 16512      // 512 guard rows + 16000
#define NLAY 20

typedef __attribute__((ext_vector_type(8))) short bf16x8;
typedef __attribute__((ext_vector_type(4))) float f32x4;
typedef __attribute__((ext_vector_type(4))) short sh4;

__device__ __forceinline__ unsigned short f2bf(float f){
  unsigned u = __float_as_uint(f);
  u += 0x7fffu + ((u >> 16) & 1u);          // RNE to bf16
  return (unsigned short)(u >> 16);
}
__device__ __forceinline__ float bf2f(unsigned short s){
  return __uint_as_float(((unsigned)s) << 16);
}
__device__ __forceinline__ void split2(float v, unsigned short& hi, unsigned short& lo){
  hi = f2bf(v);
  lo = f2bf(v - bf2f(hi));
}

#define MFMA(a,b,c) __builtin_amdgcn_mfma_f32_16x16x32_bf16((a),(b),(c),0,0,0)

// async global->LDS 16B per lane (dest = uniform base + lane*16, src per-lane)
__device__ __forceinline__ void gload16(const short* gsrc, short* ldst){
  __builtin_amdgcn_global_load_lds(
      (const __attribute__((address_space(1))) unsigned int*)gsrc,
      (__attribute__((address_space(3))) unsigned int*)ldst, 16, 0, 0);
}

// ---------------- prep kernels ----------------
__global__ void k_split(const float* __restrict__ src, short* __restrict__ hi,
                        short* __restrict__ lo, int n){
  int idx = blockIdx.x * 256 + threadIdx.x;
  if (idx < n){
    unsigned short h, l; split2(src[idx], h, l);
    hi[idx] = (short)h; lo[idx] = (short)l;
  }
}
// gate weights: Wg[l][row][k] : k<64 -> wdp[l][row][k], else wdc[l][row][k-64]
__global__ void k_split_gate(const float* __restrict__ wdp, const float* __restrict__ wdc,
                             short* __restrict__ hi, short* __restrict__ lo){
  int idx = blockIdx.x * 256 + threadIdx.x;
  if (idx < NLAY*128*128){
    int l   = idx >> 14;
    int rem = idx & 16383;
    int row = rem >> 7;
    int k   = rem & 127;
    float v = (k < 64) ? wdp[(l*128 + row)*64 + k] : wdc[(l*128 + row)*64 + (k-64)];
    unsigned short h, lo16; split2(v, h, lo16);
    hi[idx] = (short)h; lo[idx] = (short)lo16;
  }
}
// skip weights packed fragment-major: WSF[l][w][half][kb2][lane j][8]
__global__ void k_pack_wsf(const float* __restrict__ wsk, short* __restrict__ wsf){
  int idx = blockIdx.x * 256 + threadIdx.x;
  if (idx < NLAY*8*2*2*64*8){
    int e    = idx & 7;
    int j    = (idx >> 3) & 63;
    int kb2  = (idx >> 9) & 1;
    int half = (idx >> 10) & 1;
    int w    = (idx >> 11) & 7;
    int l    = idx >> 14;
    int row  = w*32 + half*16 + (j & 15);
    int ch   = (kb2*4 + (j >> 4))*8 + e;
    wsf[idx] = (short)f2bf(wsk[((size_t)l*256 + row)*64 + ch]);
  }
}
__global__ void k_bsum(const float* __restrict__ bsk, float* __restrict__ bsum){
  int s = threadIdx.x;
  if (s < 256){
    float a = 0.f;
#pragma unroll
    for (int l = 0; l < NLAY; ++l) a += bsk[l*256 + s];
    bsum[s] = a;
  }
}
// zero the 512 guard rows of both h buffers (deterministic each call)
__global__ void k_zero_guard(short* __restrict__ hA, short* __restrict__ hB){
  int idx = blockIdx.x * 256 + threadIdx.x;
  if (idx < B_*512*128){
    int b = idx / (512*128);
    int rem = idx - b*(512*128);
    size_t off = (size_t)b*HROWS*128 + rem;
    hA[off] = 0; hB[off] = 0;
  }
}

// ---------------- head-in: h = 2*(w_pre0 @ shift(x,1) + b) -> swizzled bf16 hi/lo ----------------
__global__ __launch_bounds__(512) void k_head_in(
    const float* __restrict__ x, const short* __restrict__ wph,
    const short* __restrict__ wpl, const float* __restrict__ bias,
    short* __restrict__ h)
{
  __shared__ short SXh[64*256], SXl[64*256];
  const int tid = threadIdx.x;
  const int bb = blockIdx.x / NBT;
  const int t0 = (blockIdx.x % NBT) * 64;
  const int lane = tid & 63, w = tid >> 6;
  const int l16 = lane & 15, l4 = lane >> 4;

  const float* xb = x + (size_t)bb * 256 * T_;
  {
    int col = lane;
    int t = t0 + col - 1;
#pragma unroll
    for (int p = 0; p < 16; ++p){
      int k0 = w*32 + p*2;
      float v0 = (t >= 0) ? xb[(size_t)k0*T_ + t] : 0.f;
      float v1 = (t >= 0) ? xb[(size_t)(k0+1)*T_ + t] : 0.f;
      unsigned short h0,l0,h1,l1; split2(v0,h0,l0); split2(v1,h1,l1);
      int idx = col*256 + (k0 ^ ((col & 15) << 3));
      ((unsigned int*)SXh)[idx>>1] = (unsigned)h0 | ((unsigned)h1 << 16);
      ((unsigned int*)SXl)[idx>>1] = (unsigned)l0 | ((unsigned)l1 << 16);
    }
  }
  __syncthreads();

  const int mi = w & 3, nh = w >> 2;
  const int rowA = mi*16 + l16;
  const int rt0 = mi*16 + l4*4;
  bf16x8 Ah[8], Al[8];
#pragma unroll
  for (int kb = 0; kb < 8; ++kb){
    int ko = kb*32 + l4*8;
    Ah[kb] = *(const bf16x8*)(wph + (size_t)rowA*256 + ko);
    Al[kb] = *(const bf16x8*)(wpl + (size_t)rowA*256 + ko);
  }
  short* hb = h + ((size_t)bb*HROWS + 512)*128;
#pragma unroll
  for (int nt = 0; nt < 2; ++nt){
    int col = (nh*2 + nt)*16 + l16;
    f32x4 acc = {0.f,0.f,0.f,0.f};
#pragma unroll
    for (int kb = 0; kb < 8; ++kb){
      int ko = (kb*32 + l4*8) ^ (l16 << 3);
      bf16x8 bhv = *(const bf16x8*)&SXh[col*256 + ko];
      bf16x8 blv = *(const bf16x8*)&SXl[col*256 + ko];
      acc = MFMA(Ah[kb], bhv, acc);
      acc = MFMA(Ah[kb], blv, acc);
      acc = MFMA(Al[kb], bhv, acc);
    }
    int t = t0 + col;
    int key = t & 15;
    int c  = rt0 >> 3, sub = rt0 & 7;
    sh4 hv, lv;
#pragma unroll
    for (int r = 0; r < 4; ++r){
      float v = 2.f*(acc[r] + bias[rt0 + r]);
      unsigned short hh, ll; split2(v, hh, ll);
      hv[r] = (short)hh; lv[r] = (short)ll;
    }
    *(sh4*)&hb[(size_t)t*128 + ((c ^ key) << 3) + sub] = hv;
    *(sh4*)&hb[(size_t)t*128 + (((c + 8) ^ key) << 3) + sub] = lv;
  }
}

// ---------------- per-layer kernel v6 (R16 best) ----------------
__global__ __launch_bounds__(512, 6) void k_layer6(
    const short* __restrict__ hin, short* __restrict__ hout,
    short* __restrict__ gout,     // per-layer base, tile-major [b][tile][4096] fragment order
    const short* __restrict__ wgh, const short* __restrict__ wgl,
    const short* __restrict__ wrh, const short* __restrict__ wrlo,
    const float* __restrict__ bh, const float* __restrict__ br, int d)
{
  __shared__ short SH[64*128];     // cur h rows (16KB)
  __shared__ short SHP[64*128];    // shifted h rows (16KB); SG overlay after gate
  const int tid = threadIdx.x;
  const int bb = blockIdx.x / NBT;
  const int tile = blockIdx.x % NBT;
  const int t0 = tile * 64;
  const int lane = tid & 63, w = tid >> 6;
  const int l16 = lane & 15, l4 = lane >> 4;

  const short* hb = hin + ((size_t)bb*HROWS + 512)*128;
  // async stage: wave w covers col quads 2w, 2w+1 for both tiles
  {
#pragma unroll
    for (int i = 0; i < 2; ++i){
      int colb = (w*2 + i)*4;
      const short* s1 = hb + (size_t)(t0 + colb + (lane>>4))*128 + (lane&15)*8;
      gload16(s1, &SH[colb*128]);
      const short* s2 = hb + (size_t)(t0 - d + colb + (lane>>4))*128 + (lane&15)*8;
      gload16(s2, &SHP[colb*128]);
    }
  }

  const int mi = w & 3, nh = w >> 2;
  const int rt0 = mi*16 + l4*4;
  const int rowt = mi*16 + l16, rows = 64 + mi*16 + l16;
  float bt[4], bs[4];
#pragma unroll
  for (int r = 0; r < 4; ++r){ bt[r] = bh[rt0+r]; bs[r] = bh[64+rt0+r]; }
  __syncthreads();   // drains global_load_lds (vmcnt0) + barrier

  // gate phase, K-grouped (per-accumulator MFMA order kb0,kb1,kb2,kb3 preserved)
  f32x4 at0 = {0.f,0.f,0.f,0.f}, at1 = {0.f,0.f,0.f,0.f};
  f32x4 as0 = {0.f,0.f,0.f,0.f}, as1 = {0.f,0.f,0.f,0.f};
  {  // group A: kb 0,1 -> SHP
#pragma unroll
    for (int kb = 0; kb < 2; ++kb){
      int ko = kb*32 + l4*8;
      bf16x8 Wth = *(const bf16x8*)(wgh + (size_t)rowt*128 + ko);
      bf16x8 Wtl = *(const bf16x8*)(wgl + (size_t)rowt*128 + ko);
      bf16x8 Wsh = *(const bf16x8*)(wgh + (size_t)rows*128 + ko);
      bf16x8 Wsl = *(const bf16x8*)(wgl + (size_t)rows*128 + ko);
      int cb = kb*4 + l4;
#pragma unroll
      for (int nt = 0; nt < 2; ++nt){
        int col = (nh*2 + nt)*16 + l16;
        int keyP = (col - d) & 15;
        bf16x8 bhv = *(const bf16x8*)&SHP[col*128 + ((cb ^ keyP) << 3)];
        bf16x8 blv = *(const bf16x8*)&SHP[col*128 + (((cb + 8) ^ keyP) << 3)];
        if (nt == 0){
          at0 = MFMA(Wth, bhv, at0); at0 = MFMA(Wth, blv, at0); at0 = MFMA(Wtl, bhv, at0);
          as0 = MFMA(Wsh, bhv, as0); as0 = MFMA(Wsh, blv, as0); as0 = MFMA(Wsl, bhv, as0);
        } else {
          at1 = MFMA(Wth, bhv, at1); at1 = MFMA(Wth, blv, at1); at1 = MFMA(Wtl, bhv, at1);
          as1 = MFMA(Wsh, bhv, as1); as1 = MFMA(Wsh, blv, as1); as1 = MFMA(Wsl, bhv, as1);
        }
      }
    }
  }
  {  // group B: kb 2,3 -> SH
#pragma unroll
    for (int kb = 2; kb < 4; ++kb){
      int ko = kb*32 + l4*8;
      bf16x8 Wth = *(const bf16x8*)(wgh + (size_t)rowt*128 + ko);
      bf16x8 Wtl = *(const bf16x8*)(wgl + (size_t)rowt*128 + ko);
      bf16x8 Wsh = *(const bf16x8*)(wgh + (size_t)rows*128 + ko);
      bf16x8 Wsl = *(const bf16x8*)(wgl + (size_t)rows*128 + ko);
      int cb = (kb & 1)*4 + l4;
#pragma unroll
      for (int nt = 0; nt < 2; ++nt){
        int col = (nh*2 + nt)*16 + l16;
        int keyC = col & 15;
        bf16x8 bhv = *(const bf16x8*)&SH[col*128 + ((cb ^ keyC) << 3)];
        bf16x8 blv = *(const bf16x8*)&SH[col*128 + (((cb + 8) ^ keyC) << 3)];
        if (nt == 0){
          at0 = MFMA(Wth, bhv, at0); at0 = MFMA(Wth, blv, at0); at0 = MFMA(Wtl, bhv, at0);
          as0 = MFMA(Wsh, bhv, as0); as0 = MFMA(Wsh, blv, as0); as0 = MFMA(Wsl, bhv, as0);
        } else {
          at1 = MFMA(Wth, bhv, at1); at1 = MFMA(Wth, blv, at1); at1 = MFMA(Wtl, bhv, at1);
          as1 = MFMA(Wsh, bhv, as1); as1 = MFMA(Wsh, blv, as1); as1 = MFMA(Wsl, bhv, as1);
        }
      }
    }
  }

  // nonlinearity -> packed g regs (hi/lo, 8 dwords)
  unsigned gp[2][4];
#pragma unroll
  for (int nt = 0; nt < 2; ++nt){
    unsigned short gh4[4], gl4[4];
#pragma unroll
    for (int r = 0; r < 4; ++r){
      float av = ((nt == 0) ? at0[r] : at1[r]) + bt[r];
      float sv = ((nt == 0) ? as0[r] : as1[r]) + bs[r];
      float e2 = __expf(2.f*av);
      float tv = 1.f - 2.f/(e2 + 1.f);
      float sg = 1.f/(1.f + __expf(-sv));
      float g  = tv*sg;
      split2(g, gh4[r], gl4[r]);
    }
    gp[nt][0] = (unsigned)gh4[0] | ((unsigned)gh4[1] << 16);
    gp[nt][1] = (unsigned)gh4[2] | ((unsigned)gh4[3] << 16);
    gp[nt][2] = (unsigned)gl4[0] | ((unsigned)gl4[1] << 16);
    gp[nt][3] = (unsigned)gl4[2] | ((unsigned)gl4[3] << 16);
  }
  __syncthreads();   // everyone done reading SHP

  short* SGh = SHP;          // overlay
  short* SGl = SHP + 4096;
#pragma unroll
  for (int nt = 0; nt < 2; ++nt){
    int col = (nh*2 + nt)*16 + l16;
    int gib = col*64 + (rt0 ^ ((col & 7) << 3));   // rt0+r consecutive under this XOR
    ((unsigned int*)&SGh[gib])[0] = gp[nt][0];
    ((unsigned int*)&SGh[gib])[1] = gp[nt][1];
    ((unsigned int*)&SGl[gib])[0] = gp[nt][2];
    ((unsigned int*)&SGl[gib])[1] = gp[nt][3];
  }
  __syncthreads();

  // bulk g store: fragment-major tile, 16B/thread fully coalesced.
  {
    int f = tid >> 6, j = tid & 63;
    int row = (f >> 1)*16 + (j & 15);
    int c   = (f & 1)*4 + (j >> 4);
    bf16x8 v = *(const bf16x8*)&SGh[row*64 + ((c ^ (row & 7)) << 3)];
    *(bf16x8*)(gout + ((size_t)bb*NBT + tile)*4096 + tid*8) = v;
  }

  // res phase: h_out = h_in + w_res@g + br
  {
    const int rowA = mi*16 + l16;
    bf16x8 Rh[2], Rl[2];
#pragma unroll
    for (int kb = 0; kb < 2; ++kb){
      int ko = kb*32 + l4*8;
      Rh[kb] = *(const bf16x8*)(wrh  + (size_t)rowA*64 + ko);
      Rl[kb] = *(const bf16x8*)(wrlo + (size_t)rowA*64 + ko);
    }
    short* ho = hout + ((size_t)bb*HROWS + 512)*128;
    const int cH = rt0 >> 3, sub = rt0 & 7;
#pragma unroll
    for (int nt = 0; nt < 2; ++nt){
      int col = (nh*2 + nt)*16 + l16;
      int keyC = col & 15;
      f32x4 acc = {0.f,0.f,0.f,0.f};
#pragma unroll
      for (int kb = 0; kb < 2; ++kb){
        int ko = (kb*32 + l4*8) ^ ((col & 7) << 3);
        bf16x8 bhv = *(const bf16x8*)&SGh[col*64 + ko];
        bf16x8 blv = *(const bf16x8*)&SGl[col*64 + ko];
        acc = MFMA(Rh[kb], bhv, acc);
        acc = MFMA(Rh[kb], blv, acc);
        acc = MFMA(Rl[kb], bhv, acc);
      }
      sh4 hi4 = *(const sh4*)&SH[col*128 + ((cH ^ keyC) << 3) + sub];
      sh4 lo4 = *(const sh4*)&SH[col*128 + (((cH + 8) ^ keyC) << 3) + sub];
      int t = t0 + col;
      sh4 hv, lv;
#pragma unroll
      for (int r = 0; r < 4; ++r){
        float hin_f = bf2f((unsigned short)hi4[r]) + bf2f((unsigned short)lo4[r]);
        float v = hin_f + acc[r] + br[rt0 + r];
        unsigned short hh, ll; split2(v, hh, ll);
        hv[r] = (short)hh; lv[r] = (short)ll;
      }
      *(sh4*)&ho[(size_t)t*128 + ((cH ^ keyC) << 3) + sub] = hv;
      *(sh4*)&ho[(size_t)t*128 + (((cH + 8) ^ keyC) << 3) + sub] = lv;
    }
  }
}

// ---------------- fused head (R13-proven): pipelined skip GEMM, POOL union ----------------
__global__ __launch_bounds__(512) void k_head_fused(
    float* __restrict__ io,
    const short* __restrict__ g,                // [l][b][tile][4096] fragment-major
    const short* __restrict__ wsf,              // packed skip weights [l][w][half][kb2][64][8]
    const float* __restrict__ bsum,
    const short* __restrict__ wrlh, const short* __restrict__ wrll,
    const float* __restrict__ brl,
    const short* __restrict__ woh, const short* __restrict__ wol,
    const float* __restrict__ bo)
{
  __shared__ short POOL[16384];    // union: GT[2][4096] (skip loop) | S1h[16384] | smax/ssum
  const int tid = threadIdx.x;
  const int bb = blockIdx.x / NBT;
  const int tile = blockIdx.x % NBT;
  const int t0 = tile * 64;
  const int lane = tid & 63, w = tid >> 6;
  const int l16 = lane & 15, l4 = lane >> 4;

  const int r0 = w*32 + l16, r1 = w*32 + 16 + l16;
  const int rtb0 = w*32 + l4*4, rtb1 = rtb0 + 16;

  f32x4 acc0[4], acc1[4];
#pragma unroll
  for (int nt = 0; nt < 4; ++nt){ acc0[nt] = (f32x4){0.f,0.f,0.f,0.f}; acc1[nt] = (f32x4){0.f,0.f,0.f,0.f}; }

  // ---- skip GEMM: A-loads hoisted before STAGE so vmcnt(1) keeps prefetch in flight ----
  {
    const size_t LSTR = (size_t)B_ * NBT * 4096;
    const short* gtile = g + ((size_t)bb*NBT + tile)*4096;
    const short* wb = wsf + (size_t)w*2048 + lane*8;

#define STAGE(l20, buf) gload16(gtile + (size_t)(l20)*LSTR + w*512 + lane*8, &POOL[(buf)*4096 + w*512])

    STAGE(0, 0);
    for (int l20 = 0; l20 < 20; ++l20){
      const short* wl = wb + (size_t)l20*16384;
      bf16x8 A00 = *(const bf16x8*)(wl);          // half0 kb2=0
      bf16x8 A01 = *(const bf16x8*)(wl + 512);    // half0 kb2=1
      bf16x8 A10 = *(const bf16x8*)(wl + 1024);   // half1 kb2=0
      bf16x8 A11 = *(const bf16x8*)(wl + 1536);   // half1 kb2=1
      if (l20 + 1 < 20){
        STAGE(l20 + 1, (l20 + 1) & 1);
        asm volatile("s_waitcnt vmcnt(1)" ::: "memory");
      } else {
        asm volatile("s_waitcnt vmcnt(0)" ::: "memory");
      }
      __builtin_amdgcn_s_barrier();
      __builtin_amdgcn_sched_barrier(0);
      const short* gt = &POOL[(l20 & 1)*4096];
#pragma unroll
      for (int nt = 0; nt < 4; ++nt){
        bf16x8 B0 = *(const bf16x8*)(gt + (nt*2    )*512 + lane*8);
        bf16x8 B1 = *(const bf16x8*)(gt + (nt*2 + 1)*512 + lane*8);
        acc0[nt] = MFMA(A00, B0, acc0[nt]);
        acc0[nt] = MFMA(A01, B1, acc0[nt]);
        acc1[nt] = MFMA(A10, B0, acc1[nt]);
        acc1[nt] = MFMA(A11, B1, acc1[nt]);
      }
      __builtin_amdgcn_sched_barrier(0);
      __builtin_amdgcn_s_barrier();   // protect buf (l20&1) from STAGE(l20+2)
    }
#undef STAGE
  }

  short* S1h = POOL;   // reuse (all GT reads done; last barrier above separates)
  // bias + relu -> S1h (hi only), packed dword writes
  {
    float bs0[4], bs1[4];
#pragma unroll
    for (int r = 0; r < 4; ++r){ bs0[r] = bsum[rtb0+r]; bs1[r] = bsum[rtb1+r]; }
#pragma unroll
    for (int nt = 0; nt < 4; ++nt){
      int c2 = nt*16 + l16;
      unsigned short h[4];
#pragma unroll
      for (int r = 0; r < 4; ++r)
        h[r] = f2bf(fmaxf(acc0[nt][r] + bs0[r], 0.f));
      int i0 = c2*256 + (rtb0 ^ (l16 << 3));
      ((unsigned int*)&S1h[i0])[0] = (unsigned)h[0] | ((unsigned)h[1] << 16);
      ((unsigned int*)&S1h[i0])[1] = (unsigned)h[2] | ((unsigned)h[3] << 16);
#pragma unroll
      for (int r = 0; r < 4; ++r)
        h[r] = f2bf(fmaxf(acc1[nt][r] + bs1[r], 0.f));
      int i1 = c2*256 + (rtb1 ^ (l16 << 3));
      ((unsigned int*)&S1h[i1])[0] = (unsigned)h[0] | ((unsigned)h[1] << 16);
      ((unsigned int*)&S1h[i1])[1] = (unsigned)h[2] | ((unsigned)h[3] << 16);
    }
  }
  __syncthreads();

  // GEMM1: o = wrl @ s1  (weight hi/lo x activation hi)
#pragma unroll
  for (int nt = 0; nt < 4; ++nt){ acc0[nt] = (f32x4){0.f,0.f,0.f,0.f}; acc1[nt] = (f32x4){0.f,0.f,0.f,0.f}; }
#pragma unroll
  for (int kb = 0; kb < 8; ++kb){
    int ko = kb*32 + l4*8;
    bf16x8 A0h = *(const bf16x8*)(wrlh + (size_t)r0*256 + ko);
    bf16x8 A0l = *(const bf16x8*)(wrll + (size_t)r0*256 + ko);
    bf16x8 A1h = *(const bf16x8*)(wrlh + (size_t)r1*256 + ko);
    bf16x8 A1l = *(const bf16x8*)(wrll + (size_t)r1*256 + ko);
#pragma unroll
    for (int nt = 0; nt < 4; ++nt){
      int c2 = nt*16 + l16;
      int kos = ko ^ (l16 << 3);
      bf16x8 bhv = *(const bf16x8*)&S1h[c2*256 + kos];
      acc0[nt] = MFMA(A0h, bhv, acc0[nt]);
      acc0[nt] = MFMA(A0l, bhv, acc0[nt]);
      acc1[nt] = MFMA(A1h, bhv, acc1[nt]);
      acc1[nt] = MFMA(A1l, bhv, acc1[nt]);
    }
  }
  __syncthreads();
  // relu + repack into S1h
  {
    float br0[4], br1[4];
#pragma unroll
    for (int r = 0; r < 4; ++r){ br0[r] = brl[rtb0+r]; br1[r] = brl[rtb1+r]; }
#pragma unroll
    for (int nt = 0; nt < 4; ++nt){
      int c2 = nt*16 + l16;
      unsigned short h[4];
#pragma unroll
      for (int r = 0; r < 4; ++r)
        h[r] = f2bf(fmaxf(acc0[nt][r] + br0[r], 0.f));
      int i0 = c2*256 + (rtb0 ^ (l16 << 3));
      ((unsigned int*)&S1h[i0])[0] = (unsigned)h[0] | ((unsigned)h[1] << 16);
      ((unsigned int*)&S1h[i0])[1] = (unsigned)h[2] | ((unsigned)h[3] << 16);
#pragma unroll
      for (int r = 0; r < 4; ++r)
        h[r] = f2bf(fmaxf(acc1[nt][r] + br1[r], 0.f));
      int i1 = c2*256 + (rtb1 ^ (l16 << 3));
      ((unsigned int*)&S1h[i1])[0] = (unsigned)h[0] | ((unsigned)h[1] << 16);
      ((unsigned int*)&S1h[i1])[1] = (unsigned)h[2] | ((unsigned)h[3] << 16);
    }
  }
  __syncthreads();

  // GEMM2: logits (weight hi/lo x activation hi)
#pragma unroll
  for (int nt = 0; nt < 4; ++nt){ acc0[nt] = (f32x4){0.f,0.f,0.f,0.f}; acc1[nt] = (f32x4){0.f,0.f,0.f,0.f}; }
#pragma unroll
  for (int kb = 0; kb < 8; ++kb){
    int ko = kb*32 + l4*8;
    bf16x8 A0h = *(const bf16x8*)(woh + (size_t)r0*256 + ko);
    bf16x8 A0l = *(const bf16x8*)(wol + (size_t)r0*256 + ko);
    bf16x8 A1h = *(const bf16x8*)(woh + (size_t)r1*256 + ko);
    bf16x8 A1l = *(const bf16x8*)(wol + (size_t)r1*256 + ko);
#pragma unroll
    for (int nt = 0; nt < 4; ++nt){
      int c2 = nt*16 + l16;
      int kos = ko ^ (l16 << 3);
      bf16x8 bhv = *(const bf16x8*)&S1h[c2*256 + kos];
      acc0[nt] = MFMA(A0h, bhv, acc0[nt]);
      acc0[nt] = MFMA(A0l, bhv, acc0[nt]);
      acc1[nt] = MFMA(A1h, bhv, acc1[nt]);
      acc1[nt] = MFMA(A1l, bhv, acc1[nt]);
    }
  }
  __syncthreads();   // S1h reads done before smax/ssum overlay reuse
  float* smax = (float*)POOL;             // [8][64]
  float* ssum = smax + 512;               // [8][64]
  float* iob = io + (size_t)bb * 256 * T_;
  float bo0[4], bo1[4];
#pragma unroll
  for (int r = 0; r < 4; ++r){ bo0[r] = bo[rtb0+r]; bo1[r] = bo[rtb1+r]; }
#pragma unroll
  for (int nt = 0; nt < 4; ++nt){
    float m = -1e30f;
#pragma unroll
    for (int r = 0; r < 4; ++r){
      acc0[nt][r] += bo0[r];
      acc1[nt][r] += bo1[r];
      m = fmaxf(m, fmaxf(acc0[nt][r], acc1[nt][r]));
    }
    m = fmaxf(m, __shfl_xor(m, 16, 64));
    m = fmaxf(m, __shfl_xor(m, 32, 64));
    smax[w*64 + nt*16 + l16] = m;
  }
  __syncthreads();
#pragma unroll
  for (int nt = 0; nt < 4; ++nt){
    float m = smax[nt*16 + l16];
#pragma unroll
    for (int ww = 1; ww < 8; ++ww) m = fmaxf(m, smax[ww*64 + nt*16 + l16]);
    float s = 0.f;
#pragma unroll
    for (int r = 0; r < 4; ++r){
      acc0[nt][r] = __expf(acc0[nt][r] - m); s += acc0[nt][r];
      acc1[nt][r] = __expf(acc1[nt][r] - m); s += acc1[nt][r];
    }
    s += __shfl_xor(s, 16, 64);
    s += __shfl_xor(s, 32, 64);
    ssum[w*64 + nt*16 + l16] = s;
  }
  __syncthreads();
#pragma unroll
  for (int nt = 0; nt < 4; ++nt){
    float S = 0.f;
#pragma unroll
    for (int ww = 0; ww < 8; ++ww) S += ssum[ww*64 + nt*16 + l16];
    float inv = 1.f / S;
    int t = t0 + nt*16 + l16;
#pragma unroll
    for (int r = 0; r < 4; ++r){
      iob[(size_t)(rtb0 + r)*T_ + t] = acc0[nt][r]*inv;
      iob[(size_t)(rtb1 + r)*T_ + t] = acc1[nt][r]*inv;
    }
  }
}

extern "C" void kernel_launch(void* const* d_in, const int* in_sizes, int n_in,
                              void* d_out, int out_size, void* d_ws, size_t ws_size,
                              hipStream_t stream) {
  const float* x       = (const float*)d_in[0];
  const float* w_pre0  = (const float*)d_in[1];
  const float* b_pre0  = (const float*)d_in[2];
  const float* w_dil_p = (const float*)d_in[3];
  const float* w_dil_c = (const float*)d_in[4];
  const float* bias_h  = (const float*)d_in[5];
  const float* w_res   = (const float*)d_in[6];
  const float* b_res   = (const float*)d_in[7];
  const float* w_skip  = (const float*)d_in[8];
  const float* b_skip  = (const float*)d_in[9];
  const float* w_relu  = (const float*)d_in[10];
  const float* b_relu  = (const float*)d_in[11];
  const float* w_out   = (const float*)d_in[12];
  const float* b_out   = (const float*)d_in[13];

  float* out = (float*)d_out;
  short* hA = (short*)d_ws;
  short* hB = hA + (size_t)B_ * HROWS * 128;
  float* bsum = (float*)(hB + (size_t)B_ * HROWS * 128);
  short* p   = (short*)(bsum + 256);
  short* WPh = p; p += 16384;  short* WPl = p; p += 16384;
  short* WGh = p; p += 327680; short* WGl = p; p += 327680;
  short* WRh = p; p += 81920;  short* WRl = p; p += 81920;
  short* WSF = p; p += 327680;
  short* WLh = p; p += 65536;  short* WLl = p; p += 65536;
  short* WOh = p; p += 65536;  short* WOl = p; p += 65536;
  short* GBUF = p;             // 20*8*250*4096 shorts = 327.68 MB

  // weight prep
  k_split<<<64, 256, 0, stream>>>(w_pre0, WPh, WPl, 16384);
  k_split_gate<<<1280, 256, 0, stream>>>(w_dil_p, w_dil_c, WGh, WGl);
  k_split<<<320, 256, 0, stream>>>(w_res, WRh, WRl, 81920);
  k_pack_wsf<<<1280, 256, 0, stream>>>(w_skip, WSF);
  k_split<<<256, 256, 0, stream>>>(w_relu, WLh, WLl, 65536);
  k_split<<<256, 256, 0, stream>>>(w_out, WOh, WOl, 65536);
  k_zero_guard<<<2048, 256, 0, stream>>>(hA, hB);
  k_bsum<<<1, 256, 0, stream>>>(b_skip, bsum);

  k_head_in<<<B_ * NBT, 512, 0, stream>>>(x, WPh, WPl, b_pre0, hA);

  const short* hin = hA;
  short* houtp = hB;
  for (int l = 0; l < NLAY; ++l) {
    int d = 1 << (l % 10);
    k_layer6<<<B_ * NBT, 512, 0, stream>>>(
        hin, houtp,
        GBUF + (size_t)l * B_ * NBT * 4096,
        WGh + (size_t)l*16384, WGl + (size_t)l*16384,
        WRh + (size_t)l*4096,  WRl + (size_t)l*4096,
        bias_h + (size_t)l*128, b_res + (size_t)l*64, d);
    const short* tmp = hin;
    hin = houtp;
    houtp = (short*)tmp;
  }

  k_head_fused<<<B_ * NBT, 512, 0, stream>>>(
      out, GBUF, WSF, bsum, WLh, WLl, b_relu, WOh, WOl, b_out);
}